// Round 7
// baseline (208.745 us; speedup 1.0000x reference)
//
#include <hip/hip_runtime.h>

#define N_NODES 100000
#define N_EDGES 1600000
#define IN_F    128
#define HEADS   4
#define OUT_F   16
#define HF      64
#define NEG_SLOPE 0.2f
#define NB_MFMA 1563       // ceil(N_NODES/64)

#define BUCK    56         // nodes per bucket
#define NBUCK   1786       // ceil(N_NODES/56)
#define BSTRIDE 1152       // bin slots per bucket (mean 896, +8.5 sigma)
#define BSC_CHUNK 4096
#define NB_BSC  391        // ceil(E/4096)

typedef __attribute__((ext_vector_type(8))) short short8;
typedef __attribute__((ext_vector_type(4))) float f32x4;

__device__ __forceinline__ short f2bf(float f) {
    union { float f; unsigned u; } v; v.f = f;
    return (short)((v.u + 0x7FFFu + ((v.u >> 16) & 1u)) >> 16);
}

// ---------------- k_prep: zero gcur; build bf16 B-fragments in global ----------------
// Wfrag layout: [g=ct*4+kf][lane][j] shorts, g<20. B[n=lane&15][k=(lane>>4)*8+j],
// col c = ct*16+n. ct<4: c = W row. ct==4: n<4 el-col (head n), n<8 er-col, else 0.
__global__ __launch_bounds__(256) void k_prep(const float* __restrict__ W,
                                              const float* __restrict__ attn_l,
                                              const float* __restrict__ attn_r,
                                              unsigned short* __restrict__ Wfrag,
                                              int* __restrict__ gcur) {
    __shared__ float Bext[16 * IN_F];
    int t = threadIdx.x;
    for (int i = t; i < NBUCK; i += 256) gcur[i] = 0;
    for (int o = t; o < 16 * IN_F; o += 256) {
        int c = o >> 7, k = o & 127;
        float v = 0.f;
        if (c < 8) {
            int hh = c & 3;
            const float* at = (c < 4) ? attn_l : attn_r;
            #pragma unroll
            for (int f = 0; f < 16; ++f)
                v += W[(size_t)(hh * 16 + f) * IN_F + k] * at[hh * 16 + f];
        }
        Bext[o] = v;
    }
    __syncthreads();
    for (int idx = t; idx < 20 * 64 * 8; idx += 256) {
        int j = idx & 7;
        int lane = (idx >> 3) & 63;
        int g = idx >> 9;            // ct*4 + kf
        int ct = g >> 2, kf = g & 3;
        int n = lane & 15, qq = lane >> 4;
        int k = kf * 32 + qq * 8 + j;
        float val = (ct < 4) ? W[(size_t)(ct * 16 + n) * IN_F + k]
                             : Bext[n * IN_F + k];
        Wfrag[idx] = (unsigned short)f2bf(val);
    }
}

// ---------------- k1: [z | el | er] = feats @ Bfrag via MFMA, no LDS ----------------
__global__ __launch_bounds__(256) void k1_mfma(const float* __restrict__ feats,
                                               const unsigned short* __restrict__ Wfrag,
                                               unsigned short* __restrict__ zb,
                                               float* __restrict__ el,
                                               float* __restrict__ er) {
    const int t = threadIdx.x;
    const int grp = t >> 6;            // wave = row-tile
    const int l = t & 63;
    const int q = l >> 4, n = l & 15;

    // B-fragments: coalesced 16B/lane from L1/L2-hot 20KB table
    short8 bfrag[5][4];
    #pragma unroll
    for (int ct = 0; ct < 5; ++ct)
        #pragma unroll
        for (int kf = 0; kf < 4; ++kf)
            bfrag[ct][kf] = *(const short8*)(Wfrag + (size_t)((ct * 4 + kf) * 64 + l) * 8);

    int anode = blockIdx.x * 64 + grp * 16 + n;     // A row m = n
    int aclamp = anode < N_NODES ? anode : 0;
    const float* arow = feats + (size_t)aclamp * IN_F + q * 8;

    f32x4 acc[5];
    #pragma unroll
    for (int ct = 0; ct < 5; ++ct) acc[ct] = (f32x4){0.f, 0.f, 0.f, 0.f};

    #pragma unroll
    for (int kf = 0; kf < 4; ++kf) {
        float4 x = *(const float4*)(arow + kf * 32);
        float4 y = *(const float4*)(arow + kf * 32 + 4);
        short8 a;
        a[0] = f2bf(x.x); a[1] = f2bf(x.y); a[2] = f2bf(x.z); a[3] = f2bf(x.w);
        a[4] = f2bf(y.x); a[5] = f2bf(y.y); a[6] = f2bf(y.z); a[7] = f2bf(y.w);
        #pragma unroll
        for (int ct = 0; ct < 5; ++ct)
            acc[ct] = __builtin_amdgcn_mfma_f32_16x16x32_bf16(a, bfrag[ct][kf], acc[ct], 0, 0, 0);
    }

    // epilogue: C/D col=lane&15, row=(lane>>4)*4+reg
    #pragma unroll
    for (int reg = 0; reg < 4; ++reg) {
        int onode = blockIdx.x * 64 + grp * 16 + q * 4 + reg;
        if (onode >= N_NODES) continue;
        #pragma unroll
        for (int ct = 0; ct < 4; ++ct)
            zb[(size_t)onode * HF + ct * 16 + n] = (unsigned short)f2bf(acc[ct][reg]);
        float v4 = acc[4][reg];
        if (n < 4)       el[onode * HEADS + n] = v4;
        else if (n < 8)  er[onode * HEADS + (n - 4)] = v4;
    }
}

// ---------------- block-combined bin scatter into fixed-stride buckets ----------------
// pack: src (17b) | dst%BUCK (6b) << 17
__global__ __launch_bounds__(256) void k_bsc(const int* __restrict__ src,
                                             const int* __restrict__ dst,
                                             int* __restrict__ gcur,
                                             unsigned* __restrict__ bin) {
    __shared__ int h[NBUCK], cur[NBUCK];
    int t = threadIdx.x;
    for (int i = t; i < NBUCK; i += 256) h[i] = 0;
    __syncthreads();
    int start = blockIdx.x * BSC_CHUNK;
    int end = start + BSC_CHUNK;
    if (end > N_EDGES) end = N_EDGES;
    for (int i = start + t; i < end; i += 256)
        atomicAdd(&h[(unsigned)dst[i] / BUCK], 1);
    __syncthreads();
    for (int i = t; i < NBUCK; i += 256)
        cur[i] = h[i] ? atomicAdd(&gcur[i], h[i]) : 0;
    __syncthreads();
    for (int i = start + t; i < end; i += 256) {
        unsigned d = (unsigned)dst[i];
        unsigned b = d / BUCK;
        unsigned dl = d - b * BUCK;
        int pos = atomicAdd(&cur[b], 1);
        if (pos < BSTRIDE)
            bin[(size_t)b * BSTRIDE + pos] = (unsigned)src[i] | (dl << 17);
    }
}

// ---------------- fused LDS count-sort + per-node wave aggregation ----------------
__global__ __launch_bounds__(256) void k3_sort(const unsigned* __restrict__ bin,
                                               const int* __restrict__ gcur,
                                               const float* __restrict__ el,
                                               const float* __restrict__ er,
                                               const unsigned short* __restrict__ zb,
                                               const float* __restrict__ bias,
                                               float* __restrict__ out) {
    __shared__ unsigned sorted[BSTRIDE];   // 4.5 KiB
    __shared__ int hist[BUCK];
    __shared__ int noff[BUCK + 1];
    __shared__ int cur[BUCK];
    __shared__ int s[64];
    __shared__ float er_s[BUCK * HEADS];

    const int t = threadIdx.x;
    const int b = blockIdx.x;
    const unsigned* mybin = bin + (size_t)b * BSTRIDE;
    int cnt = gcur[b];
    if (cnt > BSTRIDE) cnt = BSTRIDE;

    if (t < BUCK) hist[t] = 0;
    {
        int gbase = b * BUCK * HEADS;
        if (t < BUCK * HEADS)
            er_s[t] = (gbase + t < N_NODES * HEADS) ? er[gbase + t] : 0.f;
    }
    __syncthreads();

    for (int i = t; i < cnt; i += 256)
        atomicAdd(&hist[mybin[i] >> 17], 1);
    __syncthreads();

    // scan 56 counts on 64 slots (barriers block-uniform)
    if (t < 64) s[t] = (t < BUCK) ? hist[t] : 0;
    __syncthreads();
    for (int o = 1; o < 64; o <<= 1) {
        int x = (t < 64 && t >= o) ? s[t - o] : 0;
        __syncthreads();
        if (t < 64) s[t] += x;
        __syncthreads();
    }
    if (t < BUCK) {
        int excl = s[t] - hist[t];
        noff[t] = excl;
        cur[t] = excl;
    }
    if (t == 0) noff[BUCK] = s[BUCK - 1];
    __syncthreads();

    for (int i = t; i < cnt; i += 256) {
        unsigned p = mybin[i];
        int pos = atomicAdd(&cur[p >> 17], 1);
        sorted[pos] = p;
    }
    __syncthreads();

    const int wave = t >> 6, lane = t & 63;
    const int j = lane >> 4;        // edge slot
    const int q = lane & 15;        // channel quad
    const int h = q >> 2;           // head

    for (int nl = wave; nl < BUCK; nl += 4) {
        int node = b * BUCK + nl;
        if (node >= N_NODES) break;
        const int nlo = noff[nl], nhi = noff[nl + 1];
        const float er_d = er_s[nl * HEADS + h];

        float4 acc = make_float4(0.f, 0.f, 0.f, 0.f);
        float den = 0.f;
        for (int i = nlo + j; i < nhi; i += 4) {
            int sN = sorted[i] & 0x1FFFF;
            float x = el[sN * HEADS + h] + er_d;
            x = x > 0.f ? x : NEG_SLOPE * x;
            float ex = __expf(x);
            den += ex;
            uint2 v = *(const uint2*)(zb + (size_t)sN * HF + q * 4);
            acc.x += ex * __uint_as_float(v.x << 16);
            acc.y += ex * __uint_as_float(v.x & 0xFFFF0000u);
            acc.z += ex * __uint_as_float(v.y << 16);
            acc.w += ex * __uint_as_float(v.y & 0xFFFF0000u);
        }
        #pragma unroll
        for (int m = 16; m <= 32; m <<= 1) {
            acc.x += __shfl_xor(acc.x, m);
            acc.y += __shfl_xor(acc.y, m);
            acc.z += __shfl_xor(acc.z, m);
            acc.w += __shfl_xor(acc.w, m);
            den   += __shfl_xor(den,   m);
        }
        if (j == 0) {
            float4 bb = *(const float4*)(bias + q * 4);
            float4 o;
            if (den > 0.f) {
                float inv = 1.f / den;
                o.x = acc.x * inv + bb.x; o.y = acc.y * inv + bb.y;
                o.z = acc.z * inv + bb.z; o.w = acc.w * inv + bb.w;
            } else {
                o = bb;
            }
            *(float4*)(out + (size_t)node * HF + q * 4) = o;
        }
    }
}

extern "C" void kernel_launch(void* const* d_in, const int* in_sizes, int n_in,
                              void* d_out, int out_size, void* d_ws, size_t ws_size,
                              hipStream_t stream) {
    const float* feats  = (const float*)d_in[0];
    const float* W      = (const float*)d_in[1];
    const float* attn_l = (const float*)d_in[2];
    const float* attn_r = (const float*)d_in[3];
    const float* bias   = (const float*)d_in[4];
    const int*   src    = (const int*)d_in[5];
    const int*   dst    = (const int*)d_in[6];
    float* out = (float*)d_out;

    char* ws = (char*)d_ws;
    unsigned short* zb = (unsigned short*)ws;  ws += (size_t)N_NODES * HF * 2;
    float* el    = (float*)ws;                 ws += N_NODES * HEADS * 4;
    float* er    = (float*)ws;                 ws += N_NODES * HEADS * 4;
    unsigned short* Wfrag = (unsigned short*)ws; ws += 20 * 64 * 8 * 2;
    int*   gcur  = (int*)ws;                   ws += 2048 * 4;
    unsigned* bin = (unsigned*)ws;             ws += (size_t)NBUCK * BSTRIDE * 4;

    k_prep  <<<1,       256, 0, stream>>>(W, attn_l, attn_r, Wfrag, gcur);
    k1_mfma <<<NB_MFMA, 256, 0, stream>>>(feats, Wfrag, zb, el, er);
    k_bsc   <<<NB_BSC,  256, 0, stream>>>(src, dst, gcur, bin);
    k3_sort <<<NBUCK,   256, 0, stream>>>(bin, gcur, el, er, zb, bias, out);
}

// Round 8
// 189.508 us; speedup vs baseline: 1.1015x; 1.1015x over previous
//
#include <hip/hip_runtime.h>

#define N_NODES 100000
#define N_EDGES 1600000
#define IN_F    128
#define HEADS   4
#define OUT_F   16
#define HF      64
#define NEG_SLOPE 0.2f
#define NB_MFMA 1563       // ceil(N_NODES/64)

#define BUCK    112        // nodes per scatter bucket
#define NBUCK   893        // ceil(N_NODES/112)
#define BSTRIDE 2048       // bin slots per bucket (mean 1792)
#define BSC_CHUNK 6144
#define NB_BSC  261        // ceil(E/6144)
#define BUCK3   56         // nodes per aggregation block (half bucket)
#define K3_BLOCKS 1786     // 2*NBUCK

typedef __attribute__((ext_vector_type(8))) short short8;
typedef __attribute__((ext_vector_type(4))) float f32x4;

__device__ __forceinline__ short f2bf(float f) {
    union { float f; unsigned u; } v; v.f = f;
    return (short)((v.u + 0x7FFFu + ((v.u >> 16) & 1u)) >> 16);
}

// ---------------- k_prep: zero gcur; build bf16 B-fragments in global ----------------
__global__ __launch_bounds__(256) void k_prep(const float* __restrict__ W,
                                              const float* __restrict__ attn_l,
                                              const float* __restrict__ attn_r,
                                              unsigned short* __restrict__ Wfrag,
                                              int* __restrict__ gcur) {
    __shared__ float Bext[16 * IN_F];
    int t = threadIdx.x;
    for (int i = t; i < NBUCK; i += 256) gcur[i] = 0;
    for (int o = t; o < 16 * IN_F; o += 256) {
        int c = o >> 7, k = o & 127;
        float v = 0.f;
        if (c < 8) {
            int hh = c & 3;
            const float* at = (c < 4) ? attn_l : attn_r;
            #pragma unroll
            for (int f = 0; f < 16; ++f)
                v += W[(size_t)(hh * 16 + f) * IN_F + k] * at[hh * 16 + f];
        }
        Bext[o] = v;
    }
    __syncthreads();
    for (int idx = t; idx < 20 * 64 * 8; idx += 256) {
        int j = idx & 7;
        int lane = (idx >> 3) & 63;
        int g = idx >> 9;            // ct*4 + kf
        int ct = g >> 2, kf = g & 3;
        int n = lane & 15, qq = lane >> 4;
        int k = kf * 32 + qq * 8 + j;
        float val = (ct < 4) ? W[(size_t)(ct * 16 + n) * IN_F + k]
                             : Bext[n * IN_F + k];
        Wfrag[idx] = (unsigned short)f2bf(val);
    }
}

// ---------------- k1: [z | el | er] = feats @ Bfrag via MFMA, no LDS ----------------
__global__ __launch_bounds__(256) void k1_mfma(const float* __restrict__ feats,
                                               const unsigned short* __restrict__ Wfrag,
                                               unsigned short* __restrict__ zb,
                                               float* __restrict__ el,
                                               float* __restrict__ er) {
    const int t = threadIdx.x;
    const int grp = t >> 6;
    const int l = t & 63;
    const int q = l >> 4, n = l & 15;

    short8 bfrag[5][4];
    #pragma unroll
    for (int ct = 0; ct < 5; ++ct)
        #pragma unroll
        for (int kf = 0; kf < 4; ++kf)
            bfrag[ct][kf] = *(const short8*)(Wfrag + (size_t)((ct * 4 + kf) * 64 + l) * 8);

    int anode = blockIdx.x * 64 + grp * 16 + n;
    int aclamp = anode < N_NODES ? anode : 0;
    const float* arow = feats + (size_t)aclamp * IN_F + q * 8;

    f32x4 acc[5];
    #pragma unroll
    for (int ct = 0; ct < 5; ++ct) acc[ct] = (f32x4){0.f, 0.f, 0.f, 0.f};

    #pragma unroll
    for (int kf = 0; kf < 4; ++kf) {
        float4 x = *(const float4*)(arow + kf * 32);
        float4 y = *(const float4*)(arow + kf * 32 + 4);
        short8 a;
        a[0] = f2bf(x.x); a[1] = f2bf(x.y); a[2] = f2bf(x.z); a[3] = f2bf(x.w);
        a[4] = f2bf(y.x); a[5] = f2bf(y.y); a[6] = f2bf(y.z); a[7] = f2bf(y.w);
        #pragma unroll
        for (int ct = 0; ct < 5; ++ct)
            acc[ct] = __builtin_amdgcn_mfma_f32_16x16x32_bf16(a, bfrag[ct][kf], acc[ct], 0, 0, 0);
    }

    #pragma unroll
    for (int reg = 0; reg < 4; ++reg) {
        int onode = blockIdx.x * 64 + grp * 16 + q * 4 + reg;
        if (onode >= N_NODES) continue;
        #pragma unroll
        for (int ct = 0; ct < 4; ++ct)
            zb[(size_t)onode * HF + ct * 16 + n] = (unsigned short)f2bf(acc[ct][reg]);
        float v4 = acc[4][reg];
        if (n < 4)       el[onode * HEADS + n] = v4;
        else if (n < 8)  er[onode * HEADS + (n - 4)] = v4;
    }
}

// ---------------- block-combined bin scatter into fixed-stride buckets ----------------
// pack: src (17b) | dst%BUCK (7b) << 17
__global__ __launch_bounds__(1024) void k_bsc(const int* __restrict__ src,
                                              const int* __restrict__ dst,
                                              int* __restrict__ gcur,
                                              unsigned* __restrict__ bin) {
    __shared__ int h[NBUCK], cur[NBUCK];
    const int t = threadIdx.x;
    if (t < NBUCK) { h[t] = 0; }
    __syncthreads();
    const int start = blockIdx.x * BSC_CHUNK;
    int end = start + BSC_CHUNK;
    if (end > N_EDGES) end = N_EDGES;

    int myd[6];
    #pragma unroll
    for (int k = 0; k < 6; ++k) {
        int i = start + t + k * 1024;
        myd[k] = (i < end) ? dst[i] : -1;
        if (myd[k] >= 0) atomicAdd(&h[(unsigned)myd[k] / BUCK], 1);
    }
    __syncthreads();
    if (t < NBUCK) cur[t] = h[t] ? atomicAdd(&gcur[t], h[t]) : 0;
    __syncthreads();
    #pragma unroll
    for (int k = 0; k < 6; ++k) {
        int i = start + t + k * 1024;
        if (i < end) {
            unsigned d = (unsigned)myd[k];
            unsigned b = d / BUCK;
            unsigned dl = d - b * BUCK;
            int pos = atomicAdd(&cur[b], 1);
            if (pos < BSTRIDE)
                bin[(size_t)b * BSTRIDE + pos] = (unsigned)src[i] | (dl << 17);
        }
    }
}

// ---------------- fused LDS count-sort + aggregation: one block per HALF bucket ----------------
// lane = j*8 + c : j = edge slot (8 in flight), c = channel octet (uint4 = 8 bf16).
__global__ __launch_bounds__(256) void k3_sort(const unsigned* __restrict__ bin,
                                               const int* __restrict__ gcur,
                                               const float* __restrict__ el,
                                               const float* __restrict__ er,
                                               const unsigned short* __restrict__ zb,
                                               const float* __restrict__ bias,
                                               float* __restrict__ out) {
    __shared__ unsigned raw[BSTRIDE];      // 8 KiB
    __shared__ unsigned sorted[BSTRIDE];   // 8 KiB
    __shared__ int hist[BUCK3];
    __shared__ int noff[BUCK3 + 1];
    __shared__ int cur[BUCK3];
    __shared__ int s[64];
    __shared__ float er_s[BUCK3 * HEADS];

    const int t = threadIdx.x;
    const int B2 = blockIdx.x >> 1;
    const int half = blockIdx.x & 1;
    const int dlo = half * BUCK3;
    const int nodebase = B2 * BUCK + dlo;
    const unsigned* mybin = bin + (size_t)B2 * BSTRIDE;
    int cnt = gcur[B2];
    if (cnt > BSTRIDE) cnt = BSTRIDE;

    if (t < BUCK3) hist[t] = 0;
    if (t < BUCK3 * HEADS) {
        int g = nodebase * HEADS + t;
        er_s[t] = (g < N_NODES * HEADS) ? er[g] : 0.f;
    }
    for (int i = t; i < cnt; i += 256) raw[i] = mybin[i];
    __syncthreads();

    for (int i = t; i < cnt; i += 256) {
        int d2 = (int)(raw[i] >> 17) - dlo;
        if ((unsigned)d2 < BUCK3) atomicAdd(&hist[d2], 1);
    }
    __syncthreads();

    if (t < 64) s[t] = (t < BUCK3) ? hist[t] : 0;
    __syncthreads();
    for (int o = 1; o < 64; o <<= 1) {
        int x = (t < 64 && t >= o) ? s[t - o] : 0;
        __syncthreads();
        if (t < 64) s[t] += x;
        __syncthreads();
    }
    if (t < BUCK3) {
        int excl = s[t] - hist[t];
        noff[t] = excl;
        cur[t] = excl;
    }
    if (t == 0) noff[BUCK3] = s[BUCK3 - 1];
    __syncthreads();

    for (int i = t; i < cnt; i += 256) {
        unsigned p = raw[i];
        int d2 = (int)(p >> 17) - dlo;
        if ((unsigned)d2 < BUCK3) {
            int pos = atomicAdd(&cur[d2], 1);
            sorted[pos] = p & 0x1FFFF;     // src only
        }
    }
    __syncthreads();

    const int wave = t >> 6, lane = t & 63;
    const int j = lane >> 3;        // edge slot 0..7
    const int c = lane & 7;         // channel octet: channels c*8..c*8+7
    const int h = c >> 1;           // head

    for (int nl = wave; nl < BUCK3; nl += 4) {
        int node = nodebase + nl;
        if (node >= N_NODES) break;
        const int nlo = noff[nl], nhi = noff[nl + 1];
        const float er_d = er_s[nl * HEADS + h];

        float4 A0 = make_float4(0.f, 0.f, 0.f, 0.f);
        float4 A1 = make_float4(0.f, 0.f, 0.f, 0.f);
        float den = 0.f;
        for (int i = nlo + j; i < nhi; i += 8) {
            int sN = sorted[i];
            float x = el[sN * HEADS + h] + er_d;
            x = x > 0.f ? x : NEG_SLOPE * x;
            float ex = __expf(x);
            den += ex;
            uint4 v = *(const uint4*)(zb + (size_t)sN * HF + c * 8);
            A0.x += ex * __uint_as_float(v.x << 16);
            A0.y += ex * __uint_as_float(v.x & 0xFFFF0000u);
            A0.z += ex * __uint_as_float(v.y << 16);
            A0.w += ex * __uint_as_float(v.y & 0xFFFF0000u);
            A1.x += ex * __uint_as_float(v.z << 16);
            A1.y += ex * __uint_as_float(v.z & 0xFFFF0000u);
            A1.z += ex * __uint_as_float(v.w << 16);
            A1.w += ex * __uint_as_float(v.w & 0xFFFF0000u);
        }
        #pragma unroll
        for (int m = 8; m <= 32; m <<= 1) {
            A0.x += __shfl_xor(A0.x, m); A0.y += __shfl_xor(A0.y, m);
            A0.z += __shfl_xor(A0.z, m); A0.w += __shfl_xor(A0.w, m);
            A1.x += __shfl_xor(A1.x, m); A1.y += __shfl_xor(A1.y, m);
            A1.z += __shfl_xor(A1.z, m); A1.w += __shfl_xor(A1.w, m);
            den  += __shfl_xor(den,  m);
        }
        if (j == 0) {
            float4 b0 = *(const float4*)(bias + c * 8);
            float4 b1 = *(const float4*)(bias + c * 8 + 4);
            if (den > 0.f) {
                float inv = 1.f / den;
                b0.x += A0.x * inv; b0.y += A0.y * inv;
                b0.z += A0.z * inv; b0.w += A0.w * inv;
                b1.x += A1.x * inv; b1.y += A1.y * inv;
                b1.z += A1.z * inv; b1.w += A1.w * inv;
            }
            *(float4*)(out + (size_t)node * HF + c * 8) = b0;
            *(float4*)(out + (size_t)node * HF + c * 8 + 4) = b1;
        }
    }
}

extern "C" void kernel_launch(void* const* d_in, const int* in_sizes, int n_in,
                              void* d_out, int out_size, void* d_ws, size_t ws_size,
                              hipStream_t stream) {
    const float* feats  = (const float*)d_in[0];
    const float* W      = (const float*)d_in[1];
    const float* attn_l = (const float*)d_in[2];
    const float* attn_r = (const float*)d_in[3];
    const float* bias   = (const float*)d_in[4];
    const int*   src    = (const int*)d_in[5];
    const int*   dst    = (const int*)d_in[6];
    float* out = (float*)d_out;

    char* ws = (char*)d_ws;
    unsigned short* zb = (unsigned short*)ws;  ws += (size_t)N_NODES * HF * 2;
    float* el    = (float*)ws;                 ws += N_NODES * HEADS * 4;
    float* er    = (float*)ws;                 ws += N_NODES * HEADS * 4;
    unsigned short* Wfrag = (unsigned short*)ws; ws += 20 * 64 * 8 * 2;
    int*   gcur  = (int*)ws;                   ws += 1024 * 4;
    unsigned* bin = (unsigned*)ws;             ws += (size_t)NBUCK * BSTRIDE * 4;

    k_prep  <<<1,         256,  0, stream>>>(W, attn_l, attn_r, Wfrag, gcur);
    k1_mfma <<<NB_MFMA,   256,  0, stream>>>(feats, Wfrag, zb, el, er);
    k_bsc   <<<NB_BSC,    1024, 0, stream>>>(src, dst, gcur, bin);
    k3_sort <<<K3_BLOCKS, 256,  0, stream>>>(bin, gcur, el, er, zb, bias, out);
}